// Round 1
// 643.291 us; speedup vs baseline: 1.1263x; 1.1263x over previous
//
#include <hip/hip_runtime.h>
#include <hip/hip_bf16.h>

// MLA prefill: B=2,S=2048,D=2048,H=16,DQK=128(=64 nope+64 rope),DV=128,QLR=1536,KVLR=1024
// INPUTS FP32; OUTPUT FP32. R10:
//  (a) gemm_bt staging -> global_load_lds dwordx4 (m97 recipe), LDS linear,
//      XOR swizzle moved to pre-swizzled GLOBAL source address (m173 rule).
//  (b) attn: balanced q-tile pairing (x, 31-x) in one 512-thr/8-wave block,
//      shared K/V staging; grid 16x16x2. Worst-CU work 128 -> 66 tile-units.
//  (c) removed wave-private mid-loop barrier in attn.
// No __expf (container-killer). No INFINITY (finite-math safe).
//
// Workspace (67.7 MiB; 80MB proven writable in R1):
//   kv2 @ 0         (4096x3072 bf16, 25.2MB)  live: kv2-gemm .. attn
//   kpe @ 25165824  (4096x64  bf16,  0.5MB)   live: rope_k .. attn
//   X   @ 25690112  (16.8MB, time-shared): kvb -> qa -> attno
//   xb  @ 43319296  (4096x2048 bf16, 16.8MB)  live: cvt .. qa-gemm
//   W   @ 60096512  (8.4MB weight slot, reused: wkv_a,wkv_b,wq_a,wq_b,wo)
//   qbuf (4096x2048 bf16) lives in d_out until out-gemm.

using bf16 = __hip_bfloat16;
typedef __attribute__((ext_vector_type(8))) short bf16x8;
typedef __attribute__((ext_vector_type(4))) float f32x4;

#define S_ 2048
#define NEG_BIG (-1e30f)
#define LOG2E 1.4426950408889634f

static __device__ __forceinline__ f32x4 mfma16(bf16x8 a, bf16x8 b, f32x4 c) {
    return __builtin_amdgcn_mfma_f32_16x16x32_bf16(a, b, c, 0, 0, 0);
}

// async global->LDS, 16B per lane. LDS dest must be linear in lane order.
static __device__ __forceinline__ void gload_lds16(const bf16* g, bf16* l) {
    __builtin_amdgcn_global_load_lds(
        (const __attribute__((address_space(1))) void*)g,
        (__attribute__((address_space(3))) void*)l, 16, 0, 0);
}

// ---------------------------------------------------------------------------
// fp32 -> bf16 bulk convert, 4 elems/thread.
// ---------------------------------------------------------------------------
__global__ __launch_bounds__(256) void f2b(const float* __restrict__ src,
                                           bf16* __restrict__ dst, int n4) {
    int i = blockIdx.x * 256 + threadIdx.x;
    if (i < n4) {
        float4 v = ((const float4*)src)[i];
        alignas(8) bf16 t[4];
        t[0] = (bf16)v.x; t[1] = (bf16)v.y; t[2] = (bf16)v.z; t[3] = (bf16)v.w;
        ((uint2*)dst)[i] = *(const uint2*)t;
    }
}

// ---------------------------------------------------------------------------
// GEMM: C[M,N] = A[M,K] @ B[N,K]^T. 128x128 tile, BK=32, 256 thr, bf16 in.
// Staging via global_load_lds (async DMA). LDS layout linear in chunk index c;
// the XOR swizzle (chunkE = chunk ^ ((row>>1)&3)) is applied to the GLOBAL
// source address, so the LDS-read side keeps its conflict-reducing pattern.
// NOTE: no N-guard in staging -- caller guarantees B rows up to
// grid.y*128 are readable (ragged N=1088 reads junk rows of the 8.4MB slot;
// those columns are never stored: epilogue keeps col<N guard).
// ---------------------------------------------------------------------------
template <bool C_F32>
__global__ __launch_bounds__(256) void gemm_bt(const bf16* __restrict__ A,
                                               const bf16* __restrict__ Bw,
                                               void* __restrict__ Cv,
                                               int M, int N, int K,
                                               int lda, int ldb, int ldc) {
    __shared__ bf16 As[128 * 32];
    __shared__ bf16 Bs[128 * 32];
    const int tid = threadIdx.x;
    const int m0 = blockIdx.x * 128;
    const int n0 = blockIdx.y * 128;
    const int w = tid >> 6, lane = tid & 63, quad = lane >> 4, l15 = lane & 15;
    const int wr = (w >> 1) * 64, wc = (w & 1) * 64;

    f32x4 acc[4][4];
#pragma unroll
    for (int i = 0; i < 4; i++)
#pragma unroll
        for (int j = 0; j < 4; j++) acc[i][j] = (f32x4){0.f, 0.f, 0.f, 0.f};

    for (int k0 = 0; k0 < K; k0 += 32) {
        __syncthreads();
#pragma unroll
        for (int cc = 0; cc < 2; cc++) {
            int c = tid + cc * 256;            // 512 chunks of 8 bf16 per matrix
            int row = c >> 2;
            int chunk = (c & 3) ^ ((row >> 1) & 3);  // pre-swizzled source
            gload_lds16(A + (size_t)(m0 + row) * lda + k0 + chunk * 8, As + c * 8);
            gload_lds16(Bw + (size_t)(n0 + row) * ldb + k0 + chunk * 8, Bs + c * 8);
        }
        __syncthreads();   // compiler drains vmcnt(0) here (global_load_lds done)
        bf16x8 af[4], bfr[4];
#pragma unroll
        for (int mi = 0; mi < 4; mi++) {
            int row = wr + mi * 16 + l15;
            int chunkE = quad ^ ((row >> 1) & 3);
            af[mi] = *(const bf16x8*)(&As[row * 32 + chunkE * 8]);
        }
#pragma unroll
        for (int ni = 0; ni < 4; ni++) {
            int row = wc + ni * 16 + l15;
            int chunkE = quad ^ ((row >> 1) & 3);
            bfr[ni] = *(const bf16x8*)(&Bs[row * 32 + chunkE * 8]);
        }
#pragma unroll
        for (int mi = 0; mi < 4; mi++)
#pragma unroll
            for (int ni = 0; ni < 4; ni++)
                acc[mi][ni] = mfma16(af[mi], bfr[ni], acc[mi][ni]);
    }

#pragma unroll
    for (int mi = 0; mi < 4; mi++) {
#pragma unroll
        for (int ni = 0; ni < 4; ni++) {
            int col = n0 + wc + ni * 16 + l15;
            if (col < N) {
#pragma unroll
                for (int r = 0; r < 4; r++) {
                    int row = m0 + wr + mi * 16 + quad * 4 + r;
                    if (C_F32) ((float*)Cv)[(size_t)row * ldc + col] = acc[mi][ni][r];
                    else       ((bf16*)Cv)[(size_t)row * ldc + col] = (bf16)acc[mi][ni][r];
                }
            }
        }
    }
}

// ---------------------------------------------------------------------------
// In-place row RMSNorm on bf16 buffer, fp32 weight, fp32 stats.
// ---------------------------------------------------------------------------
__global__ void rmsnorm_ip(bf16* __restrict__ buf, const float* __restrict__ w,
                           int cols, int ld) {
    int row = blockIdx.x;
    bf16* p = buf + (size_t)row * ld;
    float ss = 0.f;
    for (int c = threadIdx.x; c < cols; c += 256) {
        float v = __bfloat162float(p[c]);
        ss += v * v;
    }
#pragma unroll
    for (int off = 32; off; off >>= 1) ss += __shfl_down(ss, off, 64);
    __shared__ float red[4];
    __shared__ float rnorm_s;
    if ((threadIdx.x & 63) == 0) red[threadIdx.x >> 6] = ss;
    __syncthreads();
    if (threadIdx.x == 0)
        rnorm_s = rsqrtf((red[0] + red[1] + red[2] + red[3]) / cols + 1e-6f);
    __syncthreads();
    float rn = rnorm_s;
    for (int c = threadIdx.x; c < cols; c += 256) {
        float v = __bfloat162float(p[c]);
        p[c] = (bf16)(v * rn * w[c]);
    }
}

// ---------------------------------------------------------------------------
// RoPE on k_pe: kpe[row,0..64) = rope(kvb[row,1024..1088)). fp32 freqs.
// ---------------------------------------------------------------------------
__global__ void rope_k(const bf16* __restrict__ kvb, bf16* __restrict__ kpe,
                       const float* __restrict__ fc, const float* __restrict__ fs) {
    int id = blockIdx.x * 256 + threadIdx.x;  // ROWS*32
    int row = id >> 5, i = id & 31;
    int s = row & (S_ - 1);
    const bf16* p = kvb + (size_t)row * 1088 + 1024 + 2 * i;
    float x0 = __bfloat162float(p[0]), x1 = __bfloat162float(p[1]);
    float c = fc[s * 32 + i], sn = fs[s * 32 + i];
    bf16* q = kpe + (size_t)row * 64 + 2 * i;
    q[0] = (bf16)(x0 * c - x1 * sn);
    q[1] = (bf16)(x0 * sn + x1 * c);
}

// RoPE on q_pe, in-place on bf16 qbuf: [row, h*128+64 .. h*128+128)
__global__ void rope_q(bf16* __restrict__ qb, const float* __restrict__ fc,
                       const float* __restrict__ fs) {
    int id = blockIdx.x * 256 + threadIdx.x;  // ROWS*16*32
    int row = id >> 9, rest = id & 511, h = rest >> 5, i = rest & 31;
    int s = row & (S_ - 1);
    bf16* p = qb + (size_t)row * 2048 + h * 128 + 64 + 2 * i;
    float x0 = __bfloat162float(p[0]), x1 = __bfloat162float(p[1]);
    float c = fc[s * 32 + i], sn = fs[s * 32 + i];
    p[0] = (bf16)(x0 * c - x1 * sn);
    p[1] = (bf16)(x0 * sn + x1 * c);
}

// ---------------------------------------------------------------------------
// MFMA flash attention, causal. BALANCED PAIRING: block x in [0,16) handles
// q-tiles jA=x (waves 0-3) and jB=31-x (waves 4-7); the two groups share
// K/V staging so per-CU work is uniform (33 tile-equivalents per block).
// 512 threads. K/V tiles of 64. Softmax in base-2 (exp2f), scores pre-scaled.
// ---------------------------------------------------------------------------
__global__ __launch_bounds__(512) void attn_kernel(const bf16* __restrict__ Qg,
                                                   const bf16* __restrict__ KV2,
                                                   const bf16* __restrict__ KPE,
                                                   bf16* __restrict__ Og) {
    __shared__ bf16 Ks[64 * 128];       // [t][d] (swizzled)
    __shared__ bf16 Vt[128 * 64];       // [dv][t] (swizzled)
    __shared__ bf16 Ps[8 * 16 * 64];    // per-wave P [m][t] (swizzled)
    const int tid = threadIdx.x;
    const int h = blockIdx.y;
    const int b = blockIdx.z;
    const int w = tid >> 6, lane = tid & 63, quad = lane >> 4, l15 = lane & 15;
    const int grp = w >> 2, wl = w & 3;
    const int jB = 31 - (int)blockIdx.x;
    const int q0 = (grp ? jB : (int)blockIdx.x) * 64;
    const float scl2 = 0.08838834764831845f * LOG2E;  // 1/sqrt(128) * log2(e)

    bf16x8 qf[4];
    {
        const bf16* qp = Qg + ((size_t)(b * S_) + q0 + wl * 16 + l15) * 2048 + h * 128 + quad * 8;
#pragma unroll
        for (int kk = 0; kk < 4; kk++) qf[kk] = *(const bf16x8*)(qp + kk * 32);
    }

    f32x4 acc_o[8];
#pragma unroll
    for (int j = 0; j < 8; j++) acc_o[j] = (f32x4){0.f, 0.f, 0.f, 0.f};
    float m_i[4], l_i[4];
#pragma unroll
    for (int r = 0; r < 4; r++) { m_i[r] = NEG_BIG; l_i[r] = 0.f; }
    const int s_base = q0 + wl * 16 + quad * 4;
    const int tend = jB * 64;           // block-uniform loop bound (barriers!)

    for (int t0 = 0; t0 <= tend; t0 += 64) {
        __syncthreads();
        // stage K: 64 x 128 = 1024 chunks of 8, 512 threads
#pragma unroll
        for (int cc = 0; cc < 2; cc++) {
            int c = tid + cc * 512;
            int trow = c >> 4, chunk = c & 15;
            int col8 = chunk * 8;
            size_t grow = (size_t)(b * S_) + t0 + trow;
            int4 v;
            if (col8 < 64) v = *(const int4*)(KV2 + grow * 3072 + h * 192 + col8);
            else           v = *(const int4*)(KPE + grow * 64 + col8 - 64);
            int chunkE = chunk ^ (trow & 7);
            *(int4*)(&Ks[trow * 128 + chunkE * 8]) = v;
        }
        // stage V transposed
#pragma unroll
        for (int cc = 0; cc < 2; cc++) {
            int c = tid + cc * 512;
            int t = c & 63, dv0 = (c >> 6) * 8;
            size_t grow = (size_t)(b * S_) + t0 + t;
            alignas(16) bf16 vals[8];
            *(int4*)vals = *(const int4*)(KV2 + grow * 3072 + h * 192 + 64 + dv0);
            int chunk = t >> 3, tl = t & 7;
#pragma unroll
            for (int j = 0; j < 8; j++) {
                int dv = dv0 + j;
                Vt[dv * 64 + (chunk ^ (dv & 7)) * 8 + tl] = vals[j];
            }
        }
        __syncthreads();
        if (t0 > q0) continue;   // this group's causal range done; keep staging

        // scores: S = Q K^T
        f32x4 sc[4];
#pragma unroll
        for (int ni = 0; ni < 4; ni++) sc[ni] = (f32x4){0.f, 0.f, 0.f, 0.f};
#pragma unroll
        for (int kk = 0; kk < 4; kk++) {
#pragma unroll
            for (int ni = 0; ni < 4; ni++) {
                int trow = ni * 16 + l15;
                int chunkE = (kk * 4 + quad) ^ (trow & 7);
                bf16x8 kf = *(const bf16x8*)(&Ks[trow * 128 + chunkE * 8]);
                sc[ni] = mfma16(qf[kk], kf, sc[ni]);
            }
        }
        // base-2 online softmax (all-finite)
        float pv[4][4], rmax[4];
#pragma unroll
        for (int r = 0; r < 4; r++) rmax[r] = NEG_BIG;
#pragma unroll
        for (int ni = 0; ni < 4; ni++) {
            int t = t0 + ni * 16 + l15;
#pragma unroll
            for (int r = 0; r < 4; r++) {
                float x = sc[ni][r] * scl2;
                if (t > s_base + r) x = NEG_BIG;
                pv[ni][r] = x;
                rmax[r] = fmaxf(rmax[r], x);
            }
        }
#pragma unroll
        for (int r = 0; r < 4; r++) {
            rmax[r] = fmaxf(rmax[r], __shfl_xor(rmax[r], 1, 64));
            rmax[r] = fmaxf(rmax[r], __shfl_xor(rmax[r], 2, 64));
            rmax[r] = fmaxf(rmax[r], __shfl_xor(rmax[r], 4, 64));
            rmax[r] = fmaxf(rmax[r], __shfl_xor(rmax[r], 8, 64));
        }
        float alpha[4], rsum[4];
#pragma unroll
        for (int r = 0; r < 4; r++) {
            float mn = fmaxf(m_i[r], rmax[r]);
            alpha[r] = exp2f(m_i[r] - mn);
            m_i[r] = mn;
            rsum[r] = 0.f;
        }
#pragma unroll
        for (int ni = 0; ni < 4; ni++)
#pragma unroll
            for (int r = 0; r < 4; r++) {
                float e = exp2f(pv[ni][r] - m_i[r]);
                pv[ni][r] = e;
                rsum[r] += e;
            }
#pragma unroll
        for (int r = 0; r < 4; r++) {
            rsum[r] += __shfl_xor(rsum[r], 1, 64);
            rsum[r] += __shfl_xor(rsum[r], 2, 64);
            rsum[r] += __shfl_xor(rsum[r], 4, 64);
            rsum[r] += __shfl_xor(rsum[r], 8, 64);
            l_i[r] = l_i[r] * alpha[r] + rsum[r];
        }
#pragma unroll
        for (int nj = 0; nj < 8; nj++)
#pragma unroll
            for (int r = 0; r < 4; r++) acc_o[nj][r] *= alpha[r];

        // P (C-layout) -> LDS (A-layout source), bf16. Wave-private region:
        // DS ops within a wave are in-order, no barrier needed before PV.
#pragma unroll
        for (int ni = 0; ni < 4; ni++) {
            int tl = ni * 16 + l15;
            int chunk = tl >> 3;
#pragma unroll
            for (int r = 0; r < 4; r++) {
                int m = quad * 4 + r;
                Ps[w * 1024 + m * 64 + (chunk ^ (m & 7)) * 8 + (tl & 7)] = (bf16)pv[ni][r];
            }
        }
        // O += P @ V
#pragma unroll
        for (int kk2 = 0; kk2 < 2; kk2++) {
            int chunkE_p = (kk2 * 4 + quad) ^ (l15 & 7);
            bf16x8 pf = *(const bf16x8*)(&Ps[w * 1024 + l15 * 64 + chunkE_p * 8]);
#pragma unroll
            for (int nj = 0; nj < 8; nj++) {
                int dv = nj * 16 + l15;
                int chunkE = (kk2 * 4 + quad) ^ (dv & 7);
                bf16x8 vf = *(const bf16x8*)(&Vt[dv * 64 + chunkE * 8]);
                acc_o[nj] = mfma16(pf, vf, acc_o[nj]);
            }
        }
    }
    // epilogue
#pragma unroll
    for (int nj = 0; nj < 8; nj++) {
        int col = h * 128 + nj * 16 + l15;
#pragma unroll
        for (int r = 0; r < 4; r++) {
            float v = acc_o[nj][r] / l_i[r];
            Og[((size_t)(b * S_) + s_base + r) * 2048 + col] = (bf16)v;
        }
    }
}

// ---------------------------------------------------------------------------
extern "C" void kernel_launch(void* const* d_in, const int* in_sizes, int n_in,
                              void* d_out, int out_size, void* d_ws, size_t ws_size,
                              hipStream_t stream) {
    const float* x        = (const float*)d_in[0];   // (4096, 2048) fp32
    const float* wq_a     = (const float*)d_in[1];   // (1536, 2048) fp32
    const float* q_norm_w = (const float*)d_in[2];   // (1536,) fp32
    const float* wq_b     = (const float*)d_in[3];   // (2048, 1536) fp32
    const float* wkv_a    = (const float*)d_in[4];   // (1088, 2048) fp32
    const float* kv_norm_w= (const float*)d_in[5];   // (1024,) fp32
    const float* wkv_b    = (const float*)d_in[6];   // (3072, 1024) fp32
    const float* wo       = (const float*)d_in[7];   // (2048, 2048) fp32
    const float* fcos     = (const float*)d_in[9];   // (2048, 32) fp32
    const float* fsin     = (const float*)d_in[10];  // (2048, 32) fp32
    float* out = (float*)d_out;                      // (4096, 2048) fp32

    char* ws = (char*)d_ws;
    bf16* kv2   = (bf16*)(ws);                  // 25.2MB
    bf16* kpe   = (bf16*)(ws + 25165824);       // 0.5MB
    bf16* kvb   = (bf16*)(ws + 25690112);       // } region X (16.8MB,
    bf16* qa    = (bf16*)(ws + 25690112);       // }  time-shared)
    bf16* attno = (bf16*)(ws + 25690112);       // }
    bf16* xb    = (bf16*)(ws + 43319296);       // 16.8MB
    bf16* wslot = (bf16*)(ws + 60096512);       // 8.4MB reusable weight slot
    bf16* qbuf  = (bf16*)d_out;                 // bf16 in d_out

    dim3 blk(256);
    // ---- convert x once ----
    f2b<<<8192, blk, 0, stream>>>(x, xb, 2097152);
    // ---- KV path ----
    f2b<<<2176, blk, 0, stream>>>(wkv_a, wslot, 557056);   // 1088*2048/4
    // N=1088 ragged: staging reads wslot rows up to 1151 (junk ok, cols>=1088
    // never stored); 1152*2048*2 = 4.72MB < 8.4MB slot.
    gemm_bt<false><<<dim3(32, 9), blk, 0, stream>>>(xb, wslot, kvb, 4096, 1088, 2048, 2048, 2048, 1088);
    rope_k<<<512, blk, 0, stream>>>(kvb, kpe, fcos, fsin);
    rmsnorm_ip<<<4096, blk, 0, stream>>>(kvb, kv_norm_w, 1024, 1088);
    f2b<<<3072, blk, 0, stream>>>(wkv_b, wslot, 786432);   // 3072*1024/4
    gemm_bt<false><<<dim3(32, 24), blk, 0, stream>>>(kvb, wslot, kv2, 4096, 3072, 1024, 1088, 1024, 3072);
    // ---- Q path (region X becomes qa; qbuf in d_out) ----
    f2b<<<3072, blk, 0, stream>>>(wq_a, wslot, 786432);    // 1536*2048/4
    gemm_bt<false><<<dim3(32, 12), blk, 0, stream>>>(xb, wslot, qa, 4096, 1536, 2048, 2048, 2048, 1536);
    rmsnorm_ip<<<4096, blk, 0, stream>>>(qa, q_norm_w, 1536, 1536);
    f2b<<<3072, blk, 0, stream>>>(wq_b, wslot, 786432);    // 2048*1536/4
    gemm_bt<false><<<dim3(32, 16), blk, 0, stream>>>(qa, wslot, qbuf, 4096, 2048, 1536, 1536, 1536, 2048);
    rope_q<<<8192, blk, 0, stream>>>(qbuf, fcos, fsin);
    // ---- attention (balanced pairing; region X becomes attno) ----
    attn_kernel<<<dim3(16, 16, 2), dim3(512), 0, stream>>>(qbuf, kv2, kpe, attno);
    // ---- output projection (fp32 store) ----
    f2b<<<4096, blk, 0, stream>>>(wo, wslot, 1048576);     // 2048*2048/4
    gemm_bt<true><<<dim3(32, 16), blk, 0, stream>>>(attno, wslot, out, 4096, 2048, 2048, 2048, 2048, 2048);
}

// Round 4
// 546.571 us; speedup vs baseline: 1.3256x; 1.1770x over previous
//
#include <hip/hip_runtime.h>
#include <hip/hip_bf16.h>

// MLA prefill: B=2,S=2048,D=2048,H=16,DQK=128(=64 nope+64 rope),DV=128,QLR=1536,KVLR=1024
// INPUTS FP32; OUTPUT FP32. R13 (bisect after R11/R12 container deaths):
//  - gemm_bt: REVERTED to R1-proven single-buffered global_load_lds staging
//    (2 barriers/K-step). The R11 double-buffer is parked pending bisection.
//  - attn: keeps SWAPPED QK^T (sc = mfma(K,Q); per-lane softmax, 2 shfl/tile,
//    packed P stores) but K staged as in R1: register int4 load from ternary
//    src + swizzled ds_write_b128 (NO divergent-base global_load_lds -- the
//    m104 wave-uniform-dest rule makes that construct hazardous under
//    if-conversion). V staged as 4x4 register transpose, 4 uint2 ds_writes.
// No __expf (container-killer). No INFINITY (finite-math safe).
//
// Workspace (67.7 MiB):
//   kv2 @ 0         (4096x3072 bf16, 25.2MB)  live: kv2-gemm .. attn
//   kpe @ 25165824  (4096x64  bf16,  0.5MB)   live: rope_k .. attn
//   X   @ 25690112  (16.8MB, time-shared): kvb -> qa -> attno
//   xb  @ 43319296  (4096x2048 bf16, 16.8MB)  live: cvt .. qa-gemm
//   W   @ 60096512  (8.4MB weight slot, reused: wkv_a,wkv_b,wq_a,wq_b,wo)
//   qbuf (4096x2048 bf16) lives in d_out until out-gemm.

using bf16 = __hip_bfloat16;
typedef __attribute__((ext_vector_type(8))) short bf16x8;
typedef __attribute__((ext_vector_type(4))) float f32x4;

#define S_ 2048
#define NEG_BIG (-1e30f)
#define LOG2E 1.4426950408889634f

static __device__ __forceinline__ f32x4 mfma16(bf16x8 a, bf16x8 b, f32x4 c) {
    return __builtin_amdgcn_mfma_f32_16x16x32_bf16(a, b, c, 0, 0, 0);
}

// async global->LDS, 16B per lane. LDS dest must be linear in lane order;
// global src must be a single affine base (no divergent base select!).
static __device__ __forceinline__ void gload_lds16(const bf16* g, bf16* l) {
    __builtin_amdgcn_global_load_lds(
        (const __attribute__((address_space(1))) void*)g,
        (__attribute__((address_space(3))) void*)l, 16, 0, 0);
}

// ---------------------------------------------------------------------------
// fp32 -> bf16 bulk convert, 4 elems/thread.
// ---------------------------------------------------------------------------
__global__ __launch_bounds__(256) void f2b(const float* __restrict__ src,
                                           bf16* __restrict__ dst, int n4) {
    int i = blockIdx.x * 256 + threadIdx.x;
    if (i < n4) {
        float4 v = ((const float4*)src)[i];
        alignas(8) bf16 t[4];
        t[0] = (bf16)v.x; t[1] = (bf16)v.y; t[2] = (bf16)v.z; t[3] = (bf16)v.w;
        ((uint2*)dst)[i] = *(const uint2*)t;
    }
}

// ---------------------------------------------------------------------------
// GEMM: C[M,N] = A[M,K] @ B[N,K]^T. 128x128 tile, BK=32, 256 thr, bf16 in.
// R1-PROVEN single-buffered staging via global_load_lds (async DMA). LDS
// linear; XOR swizzle applied to the GLOBAL source address (m173 rule).
// NOTE: no N-guard in staging -- caller guarantees B rows up to grid.y*128
// readable (ragged N=1088 reads junk rows; cols>=N never stored).
// ---------------------------------------------------------------------------
template <bool C_F32>
__global__ __launch_bounds__(256) void gemm_bt(const bf16* __restrict__ A,
                                               const bf16* __restrict__ Bw,
                                               void* __restrict__ Cv,
                                               int M, int N, int K,
                                               int lda, int ldb, int ldc) {
    __shared__ bf16 As[128 * 32];
    __shared__ bf16 Bs[128 * 32];
    const int tid = threadIdx.x;
    const int m0 = blockIdx.x * 128;
    const int n0 = blockIdx.y * 128;
    const int w = tid >> 6, lane = tid & 63, quad = lane >> 4, l15 = lane & 15;
    const int wr = (w >> 1) * 64, wc = (w & 1) * 64;

    f32x4 acc[4][4];
#pragma unroll
    for (int i = 0; i < 4; i++)
#pragma unroll
        for (int j = 0; j < 4; j++) acc[i][j] = (f32x4){0.f, 0.f, 0.f, 0.f};

    for (int k0 = 0; k0 < K; k0 += 32) {
        __syncthreads();
#pragma unroll
        for (int cc = 0; cc < 2; cc++) {
            int c = tid + cc * 256;            // 512 chunks of 8 bf16 per matrix
            int row = c >> 2;
            int chunk = (c & 3) ^ ((row >> 1) & 3);  // pre-swizzled source
            gload_lds16(A + (size_t)(m0 + row) * lda + k0 + chunk * 8, As + c * 8);
            gload_lds16(Bw + (size_t)(n0 + row) * ldb + k0 + chunk * 8, Bs + c * 8);
        }
        __syncthreads();   // drains vmcnt(0): tiles ready
        bf16x8 af[4], bfr[4];
#pragma unroll
        for (int mi = 0; mi < 4; mi++) {
            int row = wr + mi * 16 + l15;
            int chunkE = quad ^ ((row >> 1) & 3);
            af[mi] = *(const bf16x8*)(&As[row * 32 + chunkE * 8]);
        }
#pragma unroll
        for (int ni = 0; ni < 4; ni++) {
            int row = wc + ni * 16 + l15;
            int chunkE = quad ^ ((row >> 1) & 3);
            bfr[ni] = *(const bf16x8*)(&Bs[row * 32 + chunkE * 8]);
        }
#pragma unroll
        for (int mi = 0; mi < 4; mi++)
#pragma unroll
            for (int ni = 0; ni < 4; ni++)
                acc[mi][ni] = mfma16(af[mi], bfr[ni], acc[mi][ni]);
    }

#pragma unroll
    for (int mi = 0; mi < 4; mi++) {
#pragma unroll
        for (int ni = 0; ni < 4; ni++) {
            int col = n0 + wc + ni * 16 + l15;
            if (col < N) {
#pragma unroll
                for (int r = 0; r < 4; r++) {
                    int row = m0 + wr + mi * 16 + quad * 4 + r;
                    if (C_F32) ((float*)Cv)[(size_t)row * ldc + col] = acc[mi][ni][r];
                    else       ((bf16*)Cv)[(size_t)row * ldc + col] = (bf16)acc[mi][ni][r];
                }
            }
        }
    }
}

// ---------------------------------------------------------------------------
// In-place row RMSNorm on bf16 buffer, fp32 weight, fp32 stats.
// ---------------------------------------------------------------------------
__global__ void rmsnorm_ip(bf16* __restrict__ buf, const float* __restrict__ w,
                           int cols, int ld) {
    int row = blockIdx.x;
    bf16* p = buf + (size_t)row * ld;
    float ss = 0.f;
    for (int c = threadIdx.x; c < cols; c += 256) {
        float v = __bfloat162float(p[c]);
        ss += v * v;
    }
#pragma unroll
    for (int off = 32; off; off >>= 1) ss += __shfl_down(ss, off, 64);
    __shared__ float red[4];
    __shared__ float rnorm_s;
    if ((threadIdx.x & 63) == 0) red[threadIdx.x >> 6] = ss;
    __syncthreads();
    if (threadIdx.x == 0)
        rnorm_s = rsqrtf((red[0] + red[1] + red[2] + red[3]) / cols + 1e-6f);
    __syncthreads();
    float rn = rnorm_s;
    for (int c = threadIdx.x; c < cols; c += 256) {
        float v = __bfloat162float(p[c]);
        p[c] = (bf16)(v * rn * w[c]);
    }
}

// ---------------------------------------------------------------------------
// RoPE on k_pe: kpe[row,0..64) = rope(kvb[row,1024..1088)). fp32 freqs.
// ---------------------------------------------------------------------------
__global__ void rope_k(const bf16* __restrict__ kvb, bf16* __restrict__ kpe,
                       const float* __restrict__ fc, const float* __restrict__ fs) {
    int id = blockIdx.x * 256 + threadIdx.x;  // ROWS*32
    int row = id >> 5, i = id & 31;
    int s = row & (S_ - 1);
    const bf16* p = kvb + (size_t)row * 1088 + 1024 + 2 * i;
    float x0 = __bfloat162float(p[0]), x1 = __bfloat162float(p[1]);
    float c = fc[s * 32 + i], sn = fs[s * 32 + i];
    bf16* q = kpe + (size_t)row * 64 + 2 * i;
    q[0] = (bf16)(x0 * c - x1 * sn);
    q[1] = (bf16)(x0 * sn + x1 * c);
}

// RoPE on q_pe, in-place on bf16 qbuf: [row, h*128+64 .. h*128+128)
__global__ void rope_q(bf16* __restrict__ qb, const float* __restrict__ fc,
                       const float* __restrict__ fs) {
    int id = blockIdx.x * 256 + threadIdx.x;  // ROWS*16*32
    int row = id >> 9, rest = id & 511, h = rest >> 5, i = rest & 31;
    int s = row & (S_ - 1);
    bf16* p = qb + (size_t)row * 2048 + h * 128 + 64 + 2 * i;
    float x0 = __bfloat162float(p[0]), x1 = __bfloat162float(p[1]);
    float c = fc[s * 32 + i], sn = fs[s * 32 + i];
    p[0] = (bf16)(x0 * c - x1 * sn);
    p[1] = (bf16)(x0 * sn + x1 * c);
}

// ---------------------------------------------------------------------------
// MFMA flash attention, causal, SWAPPED QK^T. Block = 512 thr = 8 waves,
// 2 groups x 4 waves; group 0 q-tile blockIdx.x, group 1 q-tile 31-x (balance).
// Each lane's q-row: qrow = q0 + wl*16 + l15 (shared by the 4 quads).
// sc = mfma(K,Q) => D[t][q]: row max/sum are in-lane + shfl_xor(16|32).
// m/l are per-lane scalars; PV-space alpha/l rebroadcast via __shfl.
// K staged by REGISTER int4 + swizzled ds_write_b128 (R1-proven construct).
// ---------------------------------------------------------------------------
__global__ __launch_bounds__(512) void attn_kernel(const bf16* __restrict__ Qg,
                                                   const bf16* __restrict__ KV2,
                                                   const bf16* __restrict__ KPE,
                                                   bf16* __restrict__ Og) {
    __shared__ bf16 Ks[64 * 128];       // [t][d], 16B-chunk swizzle cE = c8 ^ (t&7)
    __shared__ bf16 Vt[128 * 64];       // [dv][t], swizzle cE = (t>>3) ^ (dv&7)
    __shared__ bf16 Ps[8][16 * 64];     // per-wave P [q16][t64], cE = c8 ^ (q&7)
    const int tid = threadIdx.x;
    const int h = blockIdx.y;
    const int b = blockIdx.z;
    const int w = tid >> 6, lane = tid & 63, quad = lane >> 4, l15 = lane & 15;
    const int grp = w >> 2, wl = w & 3;
    const int jB = 31 - (int)blockIdx.x;
    const int q0 = (grp ? jB : (int)blockIdx.x) * 64;
    const int qrow = q0 + wl * 16 + l15;          // this lane's q row (in S)
    const float scl2 = 0.08838834764831845f * LOG2E;  // 1/sqrt(128) * log2(e)

    // Q as B-fragment: lane holds col q=l15(own row), k = kk*32 + quad*8 + j
    bf16x8 qf[4];
    {
        const bf16* qp = Qg + ((size_t)(b * S_) + qrow) * 2048 + h * 128 + quad * 8;
#pragma unroll
        for (int kk = 0; kk < 4; kk++) qf[kk] = *(const bf16x8*)(qp + kk * 32);
    }

    f32x4 acc_o[8];
#pragma unroll
    for (int j = 0; j < 8; j++) acc_o[j] = (f32x4){0.f, 0.f, 0.f, 0.f};
    float m_i = NEG_BIG, l_i = 0.f;               // per-lane (q = qrow)
    const int s_base = q0 + wl * 16 + quad * 4;   // acc_o row base (PV C-layout)
    const int tend = jB * 64;                     // block-uniform loop bound

    // V staging decomposition: thread -> 4t x 4dv transpose-in-regs
    const int dv0 = (tid >> 4) * 4;               // 0..124
    const int tv0 = (tid & 15) * 4;               // 0..60

    for (int t0 = 0; t0 <= tend; t0 += 64) {
        __syncthreads();
        // ---- stage K: register int4 + swizzled ds_write (R1-proven) ----
#pragma unroll
        for (int cc = 0; cc < 2; cc++) {
            int c = tid + cc * 512;               // 1024 chunks of 8
            int trow = c >> 4, chunk = c & 15;
            int col8 = chunk * 8;
            size_t grow = (size_t)(b * S_) + t0 + trow;
            int4 v;
            if (col8 < 64) v = *(const int4*)(KV2 + grow * 3072 + h * 192 + col8);
            else           v = *(const int4*)(KPE + grow * 64 + col8 - 64);
            int chunkE = chunk ^ (trow & 7);
            *(int4*)(&Ks[trow * 128 + chunkE * 8]) = v;
        }
        // ---- stage V: 4x4 register transpose, 4 ds_write_b64/thread ----
        {
            size_t grow0 = (size_t)(b * S_) + t0 + tv0;
            alignas(16) bf16 va[4][4];
#pragma unroll
            for (int i = 0; i < 4; i++)
                *(uint2*)va[i] = *(const uint2*)(KV2 + (grow0 + i) * 3072 + h * 192 + 64 + dv0);
#pragma unroll
            for (int j = 0; j < 4; j++) {
                alignas(8) bf16 tmp[4] = {va[0][j], va[1][j], va[2][j], va[3][j]};
                int dv = dv0 + j;
                int cE = (tv0 >> 3) ^ (dv & 7);
                *(uint2*)(&Vt[dv * 64 + cE * 8 + (tv0 & 7)]) = *(uint2*)tmp;
            }
        }
        __syncthreads();
        if (t0 > q0) continue;   // this group's causal range done; keep staging

        // ---- scores, swapped: sc[ni] = K_tile(ni) x Q  => D[t][q] ----
        f32x4 sc[4];
#pragma unroll
        for (int ni = 0; ni < 4; ni++) sc[ni] = (f32x4){0.f, 0.f, 0.f, 0.f};
#pragma unroll
        for (int kk = 0; kk < 4; kk++) {
#pragma unroll
            for (int ni = 0; ni < 4; ni++) {
                int trow = ni * 16 + l15;
                int chunkE = (kk * 4 + quad) ^ (trow & 7);
                bf16x8 kf = *(const bf16x8*)(&Ks[trow * 128 + chunkE * 8]);
                sc[ni] = mfma16(kf, qf[kk], sc[ni]);   // A=K rows t, B=Q cols q
            }
        }
        // ---- per-lane softmax over the full row (t in lane) ----
        float xv[4][4];
        float pmax = NEG_BIG;
#pragma unroll
        for (int ni = 0; ni < 4; ni++) {
#pragma unroll
            for (int r = 0; r < 4; r++) {
                int t = t0 + ni * 16 + quad * 4 + r;
                float x = sc[ni][r] * scl2;
                if (t > qrow) x = NEG_BIG;
                xv[ni][r] = x;
                pmax = fmaxf(pmax, x);
            }
        }
        pmax = fmaxf(pmax, __shfl_xor(pmax, 16, 64));
        pmax = fmaxf(pmax, __shfl_xor(pmax, 32, 64));
        float mn = fmaxf(m_i, pmax);
        float alpha = exp2f(m_i - mn);
        m_i = mn;
        float rsum = 0.f;
#pragma unroll
        for (int ni = 0; ni < 4; ni++)
#pragma unroll
            for (int r = 0; r < 4; r++) {
                float e = exp2f(xv[ni][r] - mn);
                xv[ni][r] = e;
                rsum += e;
            }
        rsum += __shfl_xor(rsum, 16, 64);
        rsum += __shfl_xor(rsum, 32, 64);
        l_i = l_i * alpha + rsum;
        // alpha for acc_o rows (q-in-16 = quad*4+r) lives at lane l15=quad*4+r
        float ar[4];
#pragma unroll
        for (int r = 0; r < 4; r++) ar[r] = __shfl(alpha, quad * 4 + r, 64);
#pragma unroll
        for (int nj = 0; nj < 8; nj++)
#pragma unroll
            for (int r = 0; r < 4; r++) acc_o[nj][r] *= ar[r];

        // ---- P -> LDS: 4 packed b64 writes (t runs of 4 in-lane) ----
#pragma unroll
        for (int ni = 0; ni < 4; ni++) {
            int tb = ni * 16 + quad * 4;          // t base (elems)
            int cE = (tb >> 3) ^ (l15 & 7);
            alignas(8) bf16 tmp[4] = {(bf16)xv[ni][0], (bf16)xv[ni][1],
                                      (bf16)xv[ni][2], (bf16)xv[ni][3]};
            *(uint2*)(&Ps[w][l15 * 64 + cE * 8 + (tb & 7)]) = *(uint2*)tmp;
        }
        // ---- O += P @ V (wave-private Ps; in-wave DS ordering suffices) ----
#pragma unroll
        for (int kk2 = 0; kk2 < 2; kk2++) {
            int cEp = (kk2 * 4 + quad) ^ (l15 & 7);
            bf16x8 pf = *(const bf16x8*)(&Ps[w][l15 * 64 + cEp * 8]);
#pragma unroll
            for (int nj = 0; nj < 8; nj++) {
                int dv = nj * 16 + l15;
                int chunkE = (kk2 * 4 + quad) ^ (dv & 7);
                bf16x8 vf = *(const bf16x8*)(&Vt[dv * 64 + chunkE * 8]);
                acc_o[nj] = mfma16(pf, vf, acc_o[nj]);
            }
        }
    }
    // epilogue: l for acc rows fetched from lane l15 = quad*4+r
    float lr[4];
#pragma unroll
    for (int r = 0; r < 4; r++) lr[r] = __shfl(l_i, quad * 4 + r, 64);
#pragma unroll
    for (int nj = 0; nj < 8; nj++) {
        int col = h * 128 + nj * 16 + l15;
#pragma unroll
        for (int r = 0; r < 4; r++) {
            float v = acc_o[nj][r] / lr[r];
            Og[((size_t)(b * S_) + s_base + r) * 2048 + col] = (bf16)v;
        }
    }
}

// ---------------------------------------------------------------------------
extern "C" void kernel_launch(void* const* d_in, const int* in_sizes, int n_in,
                              void* d_out, int out_size, void* d_ws, size_t ws_size,
                              hipStream_t stream) {
    const float* x        = (const float*)d_in[0];   // (4096, 2048) fp32
    const float* wq_a     = (const float*)d_in[1];   // (1536, 2048) fp32
    const float* q_norm_w = (const float*)d_in[2];   // (1536,) fp32
    const float* wq_b     = (const float*)d_in[3];   // (2048, 1536) fp32
    const float* wkv_a    = (const float*)d_in[4];   // (1088, 2048) fp32
    const float* kv_norm_w= (const float*)d_in[5];   // (1024,) fp32
    const float* wkv_b    = (const float*)d_in[6];   // (3072, 1024) fp32
    const float* wo       = (const float*)d_in[7];   // (2048, 2048) fp32
    const float* fcos     = (const float*)d_in[9];   // (2048, 32) fp32
    const float* fsin     = (const float*)d_in[10];  // (2048, 32) fp32
    float* out = (float*)d_out;                      // (4096, 2048) fp32

    char* ws = (char*)d_ws;
    bf16* kv2   = (bf16*)(ws);                  // 25.2MB
    bf16* kpe   = (bf16*)(ws + 25165824);       // 0.5MB
    bf16* kvb   = (bf16*)(ws + 25690112);       // } region X (16.8MB,
    bf16* qa    = (bf16*)(ws + 25690112);       // }  time-shared)
    bf16* attno = (bf16*)(ws + 25690112);       // }
    bf16* xb    = (bf16*)(ws + 43319296);       // 16.8MB
    bf16* wslot = (bf16*)(ws + 60096512);       // 8.4MB reusable weight slot
    bf16* qbuf  = (bf16*)d_out;                 // bf16 in d_out

    dim3 blk(256);
    // ---- convert x once ----
    f2b<<<8192, blk, 0, stream>>>(x, xb, 2097152);
    // ---- KV path ----
    f2b<<<2176, blk, 0, stream>>>(wkv_a, wslot, 557056);   // 1088*2048/4
    // N=1088 ragged: staging reads wslot rows up to 1151 (junk ok, cols>=1088
    // never stored); 1152*2048*2 = 4.72MB < 8.4MB slot.
    gemm_bt<false><<<dim3(32, 9), blk, 0, stream>>>(xb, wslot, kvb, 4096, 1088, 2048, 2048, 2048, 1088);
    rope_k<<<512, blk, 0, stream>>>(kvb, kpe, fcos, fsin);
    rmsnorm_ip<<<4096, blk, 0, stream>>>(kvb, kv_norm_w, 1024, 1088);
    f2b<<<3072, blk, 0, stream>>>(wkv_b, wslot, 786432);   // 3072*1024/4
    gemm_bt<false><<<dim3(32, 24), blk, 0, stream>>>(kvb, wslot, kv2, 4096, 3072, 1024, 1088, 1024, 3072);
    // ---- Q path (region X becomes qa; qbuf in d_out) ----
    f2b<<<3072, blk, 0, stream>>>(wq_a, wslot, 786432);    // 1536*2048/4
    gemm_bt<false><<<dim3(32, 12), blk, 0, stream>>>(xb, wslot, qa, 4096, 1536, 2048, 2048, 2048, 1536);
    rmsnorm_ip<<<4096, blk, 0, stream>>>(qa, q_norm_w, 1536, 1536);
    f2b<<<3072, blk, 0, stream>>>(wq_b, wslot, 786432);    // 2048*1536/4
    gemm_bt<false><<<dim3(32, 16), blk, 0, stream>>>(qa, wslot, qbuf, 4096, 2048, 1536, 1536, 1536, 2048);
    rope_q<<<8192, blk, 0, stream>>>(qbuf, fcos, fsin);
    // ---- attention (balanced pairing; region X becomes attno) ----
    attn_kernel<<<dim3(16, 16, 2), dim3(512), 0, stream>>>(qbuf, kv2, kpe, attno);
    // ---- output projection (fp32 store) ----
    f2b<<<4096, blk, 0, stream>>>(wo, wslot, 1048576);     // 2048*2048/4
    gemm_bt<true><<<dim3(32, 16), blk, 0, stream>>>(attno, wslot, out, 4096, 2048, 2048, 2048, 2048, 2048);
}